// Round 18
// baseline (1095.564 us; speedup 1.0000x reference)
//
#include <hip/hip_runtime.h>
#include <stdint.h>
#include <math.h>

#define N_TOK 4096
#define H_DIM 4096
#define V_DIM 32000

// ---- 2-phase 256x256 MX-fp8 GEMM, 16 waves (4/SIMD), BK=128 ----
#define BM2 256
#define BN2 256
#define BK2 128
#define NKT2 (H_DIM / BK2)    // 32 K-tiles
#define CT2 (V_DIM / BN2)     // 125 column tiles
#define MT2 (N_TOK / BM2)     // 16 row tiles -> 2000 blocks (2000%8==0)
#define WSCALE 16.0f          // W pre-scale (avoids e4m3 subnormals)
#define WSCALE_INV 0.0625f

// ---- legacy 128x128 fallback geometry (small-ws, fp32 inputs) ----
#define BM 128
#define BN 128
#define BK 64
#define CT_NUM (V_DIM / BN)   // 250
#define MT_NUM (N_TOK / BM)   // 32

typedef __attribute__((ext_vector_type(8))) short short8;
typedef __attribute__((ext_vector_type(4))) float f32x4;
typedef __attribute__((ext_vector_type(4))) int i32x4;
typedef __attribute__((ext_vector_type(8))) int i32x8;

#define MFMA16(a, b, c) __builtin_amdgcn_mfma_f32_16x16x32_bf16(a, b, c, 0, 0, 0)
// cbsz/blgp = 0 (e4m3 A and B); scale words 0x7f7f7f7f = E8M0 exp 0 (x1.0).
#define MFMAMX(a, b, c) __builtin_amdgcn_mfma_scale_f32_16x16x128_f8f6f4( \
    a, b, c, 0, 0, 0, 0x7f7f7f7f, 0, 0x7f7f7f7f)
#define BARRIER() asm volatile("s_barrier" ::: "memory")

__device__ __forceinline__ unsigned short f2bf(float x) {
  union { float f; unsigned int u; } v; v.f = x;
  unsigned int r = v.u + 0x7fffu + ((v.u >> 16) & 1u);
  return (unsigned short)(r >> 16);
}

__device__ __forceinline__ unsigned int pk4(float a, float b, float c, float d) {
  int v = __builtin_amdgcn_cvt_pk_fp8_f32(a, b, 0, false);
  v = __builtin_amdgcn_cvt_pk_fp8_f32(c, d, v, true);
  return (unsigned int)v;
}

__device__ __forceinline__ void async16(const void* g, void* lds) {
  __builtin_amdgcn_global_load_lds(
      (const __attribute__((address_space(1))) void*)g,
      (__attribute__((address_space(3))) void*)lds, 16, 0, 0);
}

// f32 -> fp8 e4m3 with per-128-block kk-packing: slot s (16B) of block b,
// with t=s>>2, g=s&3, holds bytes [h=0: k=64t+8g+e][h=1: k=64t+32+8g+e].
// Feeding MFMAMX the i32x8 from slots {g2, 4+g2} applies the SAME
// k-permutation to A and B -> exact dot product (scales are 1.0).
__global__ __launch_bounds__(256) void cast_f32_to_fp8_k128(
    const float* __restrict__ in, uint4* __restrict__ out, long nslots,
    float scale) {
  long stride = (long)gridDim.x * blockDim.x;
  for (long slot = (long)blockIdx.x * blockDim.x + threadIdx.x; slot < nslots;
       slot += stride) {
    long b = slot >> 3;
    int s = (int)(slot & 7);
    int t = s >> 2, g = s & 3;
    const float* p0 = in + b * 128 + t * 64 + g * 8;   // h = 0
    const float* p1 = p0 + 32;                          // h = 1
    float4 a0 = *(const float4*)p0, a1 = *(const float4*)(p0 + 4);
    float4 c0 = *(const float4*)p1, c1 = *(const float4*)(p1 + 4);
    uint4 o;
    o.x = pk4(a0.x * scale, a0.y * scale, a0.z * scale, a0.w * scale);
    o.y = pk4(a1.x * scale, a1.y * scale, a1.z * scale, a1.w * scale);
    o.z = pk4(c0.x * scale, c0.y * scale, c0.z * scale, c0.w * scale);
    o.w = pk4(c1.x * scale, c1.y * scale, c1.z * scale, c1.w * scale);
    out[slot] = o;
  }
}

// Stage one 128-row x 128-B chunk (16 KB), 1024 threads, 1 DMA instr/wave.
// LDS dest linear; XOR swizzle (phys slot p holds logical slot p^(r&7))
// carried by the SOURCE address via roff.
__device__ __forceinline__ void stage8(const uint8_t* __restrict__ base,
                                       int off, char* dest, int tid) {
  async16(base + off, dest + (tid >> 6) * 1024);
}

// One 32-B f8f6f4 operand from two swizzled ds_read_b128 (r11 clean form).
__device__ __forceinline__ i32x8 ld_op(const char* base, int rowByte,
                                       int s0, int s1) {
  i32x4 lo = *(const i32x4*)(base + rowByte + s0);
  i32x4 hi = *(const i32x4*)(base + rowByte + s1);
  i32x8 r;
  r[0] = lo[0]; r[1] = lo[1]; r[2] = lo[2]; r[3] = lo[3];
  r[4] = hi[0]; r[5] = hi[1]; r[6] = hi[2]; r[7] = hi[3];
  return r;
}

// One BK=128 K-tile g, TWO phases, ONE {vmcnt(2); barrier} per tile.
// A dbuf 2x32KB: read AP=g&1, stage A(g+1) -> AP^1 in phase0. B tribuf
// 3x32KB: read BR=g%3, stage B(g+2) -> (BR+2)%3 in phase1 -- staging
// never touches a read region. Per-wave profile identical to r15 (proven
// no-spill at a 128-reg cap): acc 64 + 2 captured B frags (16) +
// rotating A (8-16). vmcnt FIFO (2A+2B=4 DMA/tile): entering phase0
// outstanding = {B(g+1) x2}; +2A -> 4; +2B -> 6; vmcnt(2) drains
// B(g+1)x2 + A(g+1)x2 (needed next tile, 1-phase slack), leaves
// {B(g+2) x2} -> invariant.
template<int AP, int BR>
__device__ __forceinline__ void tile_mx(char* lds,
    const uint8_t* __restrict__ Xbase, const uint8_t* __restrict__ Wbase,
    int roff, int ktA, int ktB, int tid,
    int aRowBase, int bRowBase, int s0, int s1, f32x4 (&acc)[4][4]) {
  const char* aB = lds + AP * 32768;
  char* aN = lds + (AP ^ 1) * 32768;
  const char* bB = lds + 65536 + BR * 32768;
  char* bN = lds + 65536 + ((BR + 2) % 3) * 32768;
  const int kA = ktA * 128, kB = ktB * 128;

  // ---- phase 0: n-frags 0,1 x all 4 m-frags; stage A(g+1) ----
  stage8(Xbase, roff + kA,               aN + 0,     tid);
  stage8(Xbase, roff + 128 * H_DIM + kA, aN + 16384, tid);
  {
    i32x8 b0 = ld_op(bB, bRowBase + 0,    s0, s1);
    i32x8 b1 = ld_op(bB, bRowBase + 2048, s0, s1);
    __builtin_amdgcn_s_setprio(1);
#pragma unroll
    for (int mf = 0; mf < 4; mf++) {
      i32x8 a = ld_op(aB, aRowBase + mf * 2048, s0, s1);
      acc[mf][0] = MFMAMX(a, b0, acc[mf][0]);
      acc[mf][1] = MFMAMX(a, b1, acc[mf][1]);
    }
    __builtin_amdgcn_s_setprio(0);
  }
  __builtin_amdgcn_sched_barrier(0);

  // ---- phase 1: n-frags 2,3 x all 4 m-frags; stage B(g+2) ----
  stage8(Wbase, roff + kB,               bN + 0,     tid);
  stage8(Wbase, roff + 128 * H_DIM + kB, bN + 16384, tid);
  {
    i32x8 b2 = ld_op(bB, bRowBase + 4096, s0, s1);
    i32x8 b3 = ld_op(bB, bRowBase + 6144, s0, s1);
    __builtin_amdgcn_s_setprio(1);
#pragma unroll
    for (int mf = 0; mf < 4; mf++) {
      i32x8 a = ld_op(aB, aRowBase + mf * 2048, s0, s1);
      acc[mf][2] = MFMAMX(a, b2, acc[mf][2]);
      acc[mf][3] = MFMAMX(a, b3, acc[mf][3]);
    }
    __builtin_amdgcn_s_setprio(0);
  }
  __builtin_amdgcn_sched_barrier(0);
  asm volatile("s_waitcnt vmcnt(2)" ::: "memory");
  BARRIER();
}

__global__ __launch_bounds__(1024, 1) void gemm_lse8(
    const uint8_t* __restrict__ Xq, const uint8_t* __restrict__ Wq,
    float* __restrict__ pmax, float* __restrict__ psum) {
  extern __shared__ char lds[];
  const int tid = threadIdx.x;
  const int lane = tid & 63;
  const int wid = tid >> 6;                // 16 waves = 4/SIMD
  const int wm = wid >> 2, wn = wid & 3;   // 4m x 4n; 64x64 out each

  // XCD-aware swizzle (2000 % 8 == 0 -> bijective), mt-fastest for W reuse.
  int logical = (blockIdx.x & 7) * (CT2 * MT2 / 8) + (blockIdx.x >> 3);
  const int ct = logical / MT2, mt = logical - ct * MT2;
  const int mbase = mt * BM2, cbase = ct * BN2;
  const uint8_t* Xbase = Xq + (size_t)mbase * H_DIM;
  const uint8_t* Wbase = Wq + (size_t)cbase * H_DIM;

  // Staging offset: row = tid>>3 (128 rows), source slot (tid&7)^(row&7).
  const int roff = (tid >> 3) * H_DIM + ((((tid & 7) ^ ((tid >> 3) & 7))) << 4);

  // r11/r15's measured-clean read form: rows lane&15 (128-B rows), two
  // b128 reads at logical slots {g2, 4+g2}, physical = slot ^ (lane&7).
  const int g2 = lane >> 4;
  const int s0 = ((g2 ^ (lane & 7)) << 4);
  const int s1 = (((4 + g2) ^ (lane & 7)) << 4);
  const int aRowBase = (wm * 64 + (lane & 15)) * 128;
  const int bRowBase = (wn * 64 + (lane & 15)) * 128;

  f32x4 acc[4][4];
#pragma unroll
  for (int i = 0; i < 4; i++)
#pragma unroll
    for (int j = 0; j < 4; j++) { f32x4 z = {0.f, 0.f, 0.f, 0.f}; acc[i][j] = z; }

  // Prologue: B(0)x2 -> bR0, A(0)x2 -> aP0, B(1)x2 -> bR1.
  // vmcnt(2) drains B(0)+A(0), leaves {B(1) x2} = steady-state invariant.
  stage8(Wbase, roff + 0,             lds + 65536 + 0,     tid);
  stage8(Wbase, roff + 128 * H_DIM,   lds + 65536 + 16384, tid);
  stage8(Xbase, roff + 0,             lds + 0,     tid);
  stage8(Xbase, roff + 128 * H_DIM,   lds + 16384, tid);
  stage8(Wbase, roff + 128,               lds + 98304 + 0,     tid);
  stage8(Wbase, roff + 128 * H_DIM + 128, lds + 98304 + 16384, tid);
  asm volatile("s_waitcnt vmcnt(2)" ::: "memory");
  BARRIER();

  // Main loop: period lcm(2,3)=6 tiles/iter; tiles 0..29, tail 30,31.
  // In-loop ktB max = 31 (no clamp); tail restages identical data into
  // non-read regions (drained by final vmcnt(0) before LDS reuse).
#pragma unroll 1
  for (int i = 0; i < 5; i++) {
    int g = 6 * i;
    tile_mx<0, 0>(lds, Xbase, Wbase, roff, g + 1, g + 2, tid,
                  aRowBase, bRowBase, s0, s1, acc);
    tile_mx<1, 1>(lds, Xbase, Wbase, roff, g + 2, g + 3, tid,
                  aRowBase, bRowBase, s0, s1, acc);
    tile_mx<0, 2>(lds, Xbase, Wbase, roff, g + 3, g + 4, tid,
                  aRowBase, bRowBase, s0, s1, acc);
    tile_mx<1, 0>(lds, Xbase, Wbase, roff, g + 4, g + 5, tid,
                  aRowBase, bRowBase, s0, s1, acc);
    tile_mx<0, 1>(lds, Xbase, Wbase, roff, g + 5, g + 6, tid,
                  aRowBase, bRowBase, s0, s1, acc);
    tile_mx<1, 2>(lds, Xbase, Wbase, roff, g + 6, g + 7, tid,
                  aRowBase, bRowBase, s0, s1, acc);
  }
  tile_mx<0, 0>(lds, Xbase, Wbase, roff, 31, 31, tid,
                aRowBase, bRowBase, s0, s1, acc);   // tile 30
  tile_mx<1, 1>(lds, Xbase, Wbase, roff, 31, 31, tid,
                aRowBase, bRowBase, s0, s1, acc);   // tile 31

  asm volatile("s_waitcnt vmcnt(0)" ::: "memory");
  __syncthreads();

  // Per-row (max, sum-exp) over this block's 256 vocab columns.
  // 16x16 C/D map (shape-determined): col = lane&15, row = (lane>>4)*4 + q.
  float2* red = (float2*)lds;   // [256 rows][4 wn]
#pragma unroll
  for (int mf = 0; mf < 4; mf++) {
#pragma unroll
    for (int qq = 0; qq < 4; qq++) {
      float v0 = acc[mf][0][qq] * WSCALE_INV, v1 = acc[mf][1][qq] * WSCALE_INV;
      float v2 = acc[mf][2][qq] * WSCALE_INV, v3 = acc[mf][3][qq] * WSCALE_INV;
      float mx = fmaxf(fmaxf(v0, v1), fmaxf(v2, v3));
#pragma unroll
      for (int d = 1; d < 16; d <<= 1) mx = fmaxf(mx, __shfl_xor(mx, d));
      float se = __expf(v0 - mx) + __expf(v1 - mx) + __expf(v2 - mx) + __expf(v3 - mx);
#pragma unroll
      for (int d = 1; d < 16; d <<= 1) se += __shfl_xor(se, d);
      if ((lane & 15) == 0) {
        int row = wm * 64 + mf * 16 + (g2 << 2) + qq;
        float2 v; v.x = mx; v.y = se;
        red[row * 4 + wn] = v;
      }
    }
  }
  __syncthreads();
  if (tid < BM2) {
    float M = -INFINITY, S = 0.f;
#pragma unroll
    for (int w = 0; w < 4; w++) {
      float2 rr = red[tid * 4 + w];
      float Mn = fmaxf(M, rr.x);
      S = S * __expf(M - Mn) + rr.y * __expf(rr.x - Mn);
      M = Mn;
    }
    size_t o = (size_t)ct * N_TOK + mbase + tid;
    pmax[o] = M;
    psum[o] = S;
  }
}

// ---------------- legacy 128^2 kernel, small-ws fallback (fp32 inputs) ------
__global__ __launch_bounds__(256) void gemm_lse_small(
    const float* __restrict__ Xf, const float* __restrict__ Wf,
    float* __restrict__ pmax, float* __restrict__ psum) {
  __shared__ unsigned short As[BM * BK];
  __shared__ unsigned short Bs[BN * BK];
  const int ct = blockIdx.x / MT_NUM;
  const int mt = blockIdx.x % MT_NUM;
  const int mbase = mt * BM, cbase = ct * BN;
  const int tid = threadIdx.x;
  const int lane = tid & 63;
  const int wid = tid >> 6;
  const int wr = wid >> 1, wc = wid & 1;
  f32x4 acc[4][4];
#pragma unroll
  for (int i = 0; i < 4; i++)
#pragma unroll
    for (int j = 0; j < 4; j++) { f32x4 z = {0.f, 0.f, 0.f, 0.f}; acc[i][j] = z; }
  for (int ks = 0; ks < H_DIM / BK; ks++) {
    const int k0 = ks * BK;
#pragma unroll
    for (int r = 0; r < 4; r++) {
      int o = r * 4096 + wid * 1024 + lane * 16;
      int row = o >> 7;
      int kc = (o & 127) >> 1;
      const float* xs = Xf + (size_t)(mbase + row) * H_DIM + k0 + kc;
      const float* wv = Wf + (size_t)(cbase + row) * H_DIM + k0 + kc;
      float4 x0 = *(const float4*)xs, x1 = *(const float4*)(xs + 4);
      float4 w0 = *(const float4*)wv, w1 = *(const float4*)(wv + 4);
      short8 xa, wa;
      xa[0] = f2bf(x0.x); xa[1] = f2bf(x0.y); xa[2] = f2bf(x0.z); xa[3] = f2bf(x0.w);
      xa[4] = f2bf(x1.x); xa[5] = f2bf(x1.y); xa[6] = f2bf(x1.z); xa[7] = f2bf(x1.w);
      wa[0] = f2bf(w0.x); wa[1] = f2bf(w0.y); wa[2] = f2bf(w0.z); wa[3] = f2bf(w0.w);
      wa[4] = f2bf(w1.x); wa[5] = f2bf(w1.y); wa[6] = f2bf(w1.z); wa[7] = f2bf(w1.w);
      *(short8*)((char*)As + o) = xa;
      *(short8*)((char*)Bs + o) = wa;
    }
    __syncthreads();
#pragma unroll
    for (int kk = 0; kk < 2; kk++) {
      short8 a[4], b[4];
#pragma unroll
      for (int m = 0; m < 4; m++)
        a[m] = *(const short8*)((const char*)As +
                (wr * 64 + m * 16 + (lane & 15)) * 128 + kk * 64 + (lane >> 4) * 16);
#pragma unroll
      for (int n = 0; n < 4; n++)
        b[n] = *(const short8*)((const char*)Bs +
                (wc * 64 + n * 16 + (lane & 15)) * 128 + kk * 64 + (lane >> 4) * 16);
#pragma unroll
      for (int m = 0; m < 4; m++)
#pragma unroll
        for (int n = 0; n < 4; n++)
          acc[m][n] = MFMA16(a[m], b[n], acc[m][n]);
    }
    __syncthreads();
  }
  float* red = (float*)As;
  const int g = lane >> 4;
#pragma unroll
  for (int m = 0; m < 4; m++) {
#pragma unroll
    for (int q = 0; q < 4; q++) {
      float v0 = acc[m][0][q], v1 = acc[m][1][q], v2 = acc[m][2][q], v3 = acc[m][3][q];
      float mx = fmaxf(fmaxf(v0, v1), fmaxf(v2, v3));
#pragma unroll
      for (int d = 1; d < 16; d <<= 1) mx = fmaxf(mx, __shfl_xor(mx, d));
      float se = __expf(v0 - mx) + __expf(v1 - mx) + __expf(v2 - mx) + __expf(v3 - mx);
#pragma unroll
      for (int d = 1; d < 16; d <<= 1) se += __shfl_xor(se, d);
      if ((lane & 15) == 0) {
        int row = wr * 64 + m * 16 + g * 4 + q;
        red[row * 4 + wc * 2 + 0] = mx;
        red[row * 4 + wc * 2 + 1] = se;
      }
    }
  }
  __syncthreads();
  if (tid < BM) {
    float m0 = red[tid * 4 + 0], s0 = red[tid * 4 + 1];
    float m1 = red[tid * 4 + 2], s1 = red[tid * 4 + 3];
    float M = fmaxf(m0, m1);
    float S = s0 * __expf(m0 - M) + s1 * __expf(m1 - M);
    size_t o = (size_t)ct * N_TOK + mbase + tid;
    pmax[o] = M;
    psum[o] = S;
  }
}

// ---------------- exact fp32 target logit + reduction kernels ---------------
__global__ __launch_bounds__(256) void target_logit(
    const float* __restrict__ X, const float* __restrict__ W,
    const int* __restrict__ y, float* __restrict__ tl) {
  __shared__ float red[4];
  int row = blockIdx.x;
  int lab = y[row];
  float s = 0.f;
  if (lab >= 0 && lab < V_DIM) {
    const float4* xr = (const float4*)(X + (size_t)row * H_DIM);
    const float4* wr = (const float4*)(W + (size_t)lab * H_DIM);
    for (int i = threadIdx.x; i < H_DIM / 4; i += 256) {
      float4 a = xr[i], b = wr[i];
      s += a.x * b.x + a.y * b.y + a.z * b.z + a.w * b.w;
    }
  }
#pragma unroll
  for (int o = 32; o > 0; o >>= 1) s += __shfl_down(s, o);
  if ((threadIdx.x & 63) == 0) red[threadIdx.x >> 6] = s;
  __syncthreads();
  if (threadIdx.x == 0) tl[row] = red[0] + red[1] + red[2] + red[3];
}

__global__ __launch_bounds__(256) void combine_rows(
    const float* __restrict__ pmax, const float* __restrict__ psum,
    const float* __restrict__ tl, const int* __restrict__ y,
    float* __restrict__ lossb, float* __restrict__ validb, int n_ct) {
  int row = blockIdx.x * 256 + threadIdx.x;
  if (row >= N_TOK) return;
  float M = -INFINITY, S = 0.f;
  for (int ct = 0; ct < n_ct; ct++) {
    float m = pmax[(size_t)ct * N_TOK + row];
    float s = psum[(size_t)ct * N_TOK + row];
    float Mn = fmaxf(M, m);
    S = S * __expf(M - Mn) + s * __expf(m - Mn);
    M = Mn;
  }
  bool valid = (y[row] != -100);
  lossb[row] = valid ? (M + __logf(S) - tl[row]) : 0.f;
  validb[row] = valid ? 1.f : 0.f;
}

__global__ __launch_bounds__(256) void finalize_loss(
    const float* __restrict__ lossb, const float* __restrict__ validb,
    float* __restrict__ out) {
  __shared__ float rs[4], rc[4];
  float s = 0.f, c = 0.f;
  for (int i = threadIdx.x; i < N_TOK; i += 256) { s += lossb[i]; c += validb[i]; }
#pragma unroll
  for (int o = 32; o > 0; o >>= 1) { s += __shfl_down(s, o); c += __shfl_down(c, o); }
  if ((threadIdx.x & 63) == 0) { rs[threadIdx.x >> 6] = s; rc[threadIdx.x >> 6] = c; }
  __syncthreads();
  if (threadIdx.x == 0) {
    float S = rs[0] + rs[1] + rs[2] + rs[3];
    float C = rc[0] + rc[1] + rc[2] + rc[3];
    out[0] = S / fmaxf(C, 1.f);
  }
}

extern "C" void kernel_launch(void* const* d_in, const int* in_sizes, int n_in,
                              void* d_out, int out_size, void* d_ws, size_t ws_size,
                              hipStream_t stream) {
  const float* x = (const float*)d_in[0];
  const int* y = (const int*)d_in[1];
  const float* W = (const float*)d_in[2];
  float* out = (float*)d_out;
  char* ws = (char*)d_ws;

  const size_t szWq = (size_t)V_DIM * H_DIM;        // 131,072,000 (fp8)
  const size_t szXq = (size_t)N_TOK * H_DIM;        //  16,777,216 (fp8)
  const size_t szP  = (size_t)CT_NUM * N_TOK * 4;   // sized for 250-tile fallback
  const size_t szT  = (size_t)N_TOK * 4;
  const size_t needFull = szWq + szXq + 2 * szP + 3 * szT;

  bool full = (ws_size >= needFull);
  uint8_t* Wq = nullptr;
  uint8_t* Xq = nullptr;
  size_t off = 0;
  if (full) { Wq = (uint8_t*)ws; Xq = (uint8_t*)(ws + szWq); off = szWq + szXq; }
  float* pmax   = (float*)(ws + off); off += szP;
  float* psum   = (float*)(ws + off); off += szP;
  float* tl     = (float*)(ws + off); off += szT;
  float* lossb  = (float*)(ws + off); off += szT;
  float* validb = (float*)(ws + off);

  if (full) {
    cast_f32_to_fp8_k128<<<8192, 256, 0, stream>>>(
        W, (uint4*)Wq, (long)(szWq / 16), WSCALE);
    cast_f32_to_fp8_k128<<<2048, 256, 0, stream>>>(
        x, (uint4*)Xq, (long)(szXq / 16), 1.0f);
    (void)hipFuncSetAttribute((const void*)gemm_lse8,
        hipFuncAttributeMaxDynamicSharedMemorySize, 163840);
    gemm_lse8<<<CT2 * MT2, 1024, 163840, stream>>>(Xq, Wq, pmax, psum);
    target_logit<<<N_TOK, 256, 0, stream>>>(x, W, y, tl);
    combine_rows<<<N_TOK / 256, 256, 0, stream>>>(pmax, psum, tl, y, lossb, validb, CT2);
  } else {
    gemm_lse_small<<<CT_NUM * MT_NUM, 256, 0, stream>>>(x, W, pmax, psum);
    target_logit<<<N_TOK, 256, 0, stream>>>(x, W, y, tl);
    combine_rows<<<N_TOK / 256, 256, 0, stream>>>(pmax, psum, tl, y, lossb, validb, CT_NUM);
  }
  finalize_loss<<<1, 256, 0, stream>>>(lossb, validb, out);
}

// Round 19
// 770.775 us; speedup vs baseline: 1.4214x; 1.4214x over previous
//
#include <hip/hip_runtime.h>
#include <stdint.h>
#include <math.h>

#define N_TOK 4096
#define H_DIM 4096
#define V_DIM 32000

// ---- 2-phase 128x256 MX-fp8 GEMM geometry (BK=128, kk-packed slots) ----
#define BM2 128
#define BN2 256
#define BK2 128
#define NKT2 (H_DIM / BK2)    // 32 K-tiles
#define CT2 (V_DIM / BN2)     // 125 column tiles
#define MT2 (N_TOK / BM2)     // 32 row tiles -> 4000 blocks (4000%8==0)
#define WSCALE 16.0f          // W pre-scale (avoids e4m3 subnormals)
#define WSCALE_INV 0.0625f

// ---- legacy 128x128 fallback geometry (small-ws, fp32 inputs) ----
#define BM 128
#define BN 128
#define BK 64
#define CT_NUM (V_DIM / BN)   // 250
#define MT_NUM (N_TOK / BM)   // 32

typedef __attribute__((ext_vector_type(8))) short short8;
typedef __attribute__((ext_vector_type(4))) float f32x4;
typedef __attribute__((ext_vector_type(4))) int i32x4;
typedef __attribute__((ext_vector_type(8))) int i32x8;

#define MFMA16(a, b, c) __builtin_amdgcn_mfma_f32_16x16x32_bf16(a, b, c, 0, 0, 0)
// cbsz/blgp = 0 (e4m3 A and B); scale words 0x7f7f7f7f = E8M0 exp 0 (x1.0).
#define MFMAMX(a, b, c) __builtin_amdgcn_mfma_scale_f32_16x16x128_f8f6f4( \
    a, b, c, 0, 0, 0, 0x7f7f7f7f, 0, 0x7f7f7f7f)
#define BARRIER() asm volatile("s_barrier" ::: "memory")

__device__ __forceinline__ unsigned short f2bf(float x) {
  union { float f; unsigned int u; } v; v.f = x;
  unsigned int r = v.u + 0x7fffu + ((v.u >> 16) & 1u);
  return (unsigned short)(r >> 16);
}

__device__ __forceinline__ unsigned int pk4(float a, float b, float c, float d) {
  int v = __builtin_amdgcn_cvt_pk_fp8_f32(a, b, 0, false);
  v = __builtin_amdgcn_cvt_pk_fp8_f32(c, d, v, true);
  return (unsigned int)v;
}

__device__ __forceinline__ void async16(const void* g, void* lds) {
  __builtin_amdgcn_global_load_lds(
      (const __attribute__((address_space(1))) void*)g,
      (__attribute__((address_space(3))) void*)lds, 16, 0, 0);
}

// f32 -> fp8 e4m3 with per-128-block kk-packing: slot s (16B) of block b,
// with t=s>>2, g=s&3, holds bytes [h=0: k=64t+8g+e][h=1: k=64t+32+8g+e].
// Feeding MFMAMX the i32x8 from slots {g2, 4+g2} applies the SAME
// k-permutation to A and B -> exact dot product (scales are 1.0).
__global__ __launch_bounds__(256) void cast_f32_to_fp8_k128(
    const float* __restrict__ in, uint4* __restrict__ out, long nslots,
    float scale) {
  long stride = (long)gridDim.x * blockDim.x;
  for (long slot = (long)blockIdx.x * blockDim.x + threadIdx.x; slot < nslots;
       slot += stride) {
    long b = slot >> 3;
    int s = (int)(slot & 7);
    int t = s >> 2, g = s & 3;
    const float* p0 = in + b * 128 + t * 64 + g * 8;   // h = 0
    const float* p1 = p0 + 32;                          // h = 1
    float4 a0 = *(const float4*)p0, a1 = *(const float4*)(p0 + 4);
    float4 c0 = *(const float4*)p1, c1 = *(const float4*)(p1 + 4);
    uint4 o;
    o.x = pk4(a0.x * scale, a0.y * scale, a0.z * scale, a0.w * scale);
    o.y = pk4(a1.x * scale, a1.y * scale, a1.z * scale, a1.w * scale);
    o.z = pk4(c0.x * scale, c0.y * scale, c0.z * scale, c0.w * scale);
    o.w = pk4(c1.x * scale, c1.y * scale, c1.z * scale, c1.w * scale);
    out[slot] = o;
  }
}

// Stage one 64-row x 128-B chunk (8 KB), 512 threads, 1 DMA instr/wave.
// LDS dest linear; XOR swizzle (phys slot p holds logical slot p^(r&7))
// carried by the SOURCE address via roff.
__device__ __forceinline__ void stage8(const uint8_t* __restrict__ base,
                                       int off, char* dest, int tid) {
  async16(base + off, dest + (tid >> 6) * 1024);
}

// One 32-B f8f6f4 operand from two swizzled ds_read_b128 (r11 clean form).
__device__ __forceinline__ i32x8 ld_op(const char* base, int rowByte,
                                       int s0, int s1) {
  i32x4 lo = *(const i32x4*)(base + rowByte + s0);
  i32x4 hi = *(const i32x4*)(base + rowByte + s1);
  i32x8 r;
  r[0] = lo[0]; r[1] = lo[1]; r[2] = lo[2]; r[3] = lo[3];
  r[4] = hi[0]; r[5] = hi[1]; r[6] = hi[2]; r[7] = hi[3];
  return r;
}

// One BK=128 K-tile g, TWO phases, ONE {vmcnt(4); barrier} per tile.
// A dbuf 2x16KB: read AP=g&1, stage A(g+1) -> AP^1 in phase0. B tribuf
// 3x32KB: read BR=g%3, stage B(g+2) -> (BR+2)%3 in phase1 -- staging
// never touches a read region. Per-phase operands: 2 captured B-frags
// (16 regs) + rotating A-frag (8-16) + acc 64 -> ~112 arch regs, no spill
// (proven r15: VGPR 124). vmcnt FIFO (2A+4B=6 DMA/tile): entering phase0
// outstanding = {B(g+1) x4}; +2A -> 6; +4B -> 10; vmcnt(4) drains
// B(g+1)x4 + A(g+1)x2 (needed next tile, ~1-phase slack), leaves
// {B(g+2) x4} -> invariant.
template<int AP, int BR>
__device__ __forceinline__ void tile_mx(char* lds,
    const uint8_t* __restrict__ Xbase, const uint8_t* __restrict__ Wbase,
    int roff, int ktA, int ktB, int tid,
    int aRowBase, int bRowBase, int s0, int s1, f32x4 (&acc)[4][4]) {
  const char* aB = lds + AP * 16384;
  char* aN = lds + (AP ^ 1) * 16384;
  const char* bB = lds + 32768 + BR * 32768;
  char* bN = lds + 32768 + ((BR + 2) % 3) * 32768;
  const int kA = ktA * 128, kB = ktB * 128;

  // ---- phase 0: n-frags 0,1 x all 4 m-frags; stage A(g+1) ----
  stage8(Xbase, roff + kA,              aN + 0,    tid);
  stage8(Xbase, roff + 64 * H_DIM + kA, aN + 8192, tid);
  {
    i32x8 b0 = ld_op(bB, bRowBase + 0,    s0, s1);
    i32x8 b1 = ld_op(bB, bRowBase + 2048, s0, s1);
    __builtin_amdgcn_s_setprio(1);
#pragma unroll
    for (int mf = 0; mf < 4; mf++) {
      i32x8 a = ld_op(aB, aRowBase + mf * 2048, s0, s1);
      acc[mf][0] = MFMAMX(a, b0, acc[mf][0]);
      acc[mf][1] = MFMAMX(a, b1, acc[mf][1]);
    }
    __builtin_amdgcn_s_setprio(0);
  }
  __builtin_amdgcn_sched_barrier(0);

  // ---- phase 1: n-frags 2,3 x all 4 m-frags; stage B(g+2) ----
  stage8(Wbase, roff + kB,               bN + 0,     tid);
  stage8(Wbase, roff + 64 * H_DIM + kB,  bN + 8192,  tid);
  stage8(Wbase, roff + 128 * H_DIM + kB, bN + 16384, tid);
  stage8(Wbase, roff + 192 * H_DIM + kB, bN + 24576, tid);
  {
    i32x8 b2 = ld_op(bB, bRowBase + 4096, s0, s1);
    i32x8 b3 = ld_op(bB, bRowBase + 6144, s0, s1);
    __builtin_amdgcn_s_setprio(1);
#pragma unroll
    for (int mf = 0; mf < 4; mf++) {
      i32x8 a = ld_op(aB, aRowBase + mf * 2048, s0, s1);
      acc[mf][2] = MFMAMX(a, b2, acc[mf][2]);
      acc[mf][3] = MFMAMX(a, b3, acc[mf][3]);
    }
    __builtin_amdgcn_s_setprio(0);
  }
  __builtin_amdgcn_sched_barrier(0);
  asm volatile("s_waitcnt vmcnt(4)" ::: "memory");
  BARRIER();
}

__global__ __launch_bounds__(512, 2) void gemm_lse8(
    const uint8_t* __restrict__ Xq, const uint8_t* __restrict__ Wq,
    float* __restrict__ pmax, float* __restrict__ psum) {
  extern __shared__ char lds[];
  const int tid = threadIdx.x;
  const int lane = tid & 63;
  const int wid = tid >> 6;
  const int wm = wid >> 2, wn = wid & 3;   // 2m x 4n waves; 64x64 out each

  // XCD-aware swizzle (4000 % 8 == 0 -> bijective), mt-fastest for W reuse.
  int logical = (blockIdx.x & 7) * (CT2 * MT2 / 8) + (blockIdx.x >> 3);
  const int ct = logical / MT2, mt = logical - ct * MT2;
  const int mbase = mt * BM2, cbase = ct * BN2;
  const uint8_t* Xbase = Xq + (size_t)mbase * H_DIM;
  const uint8_t* Wbase = Wq + (size_t)cbase * H_DIM;

  // Staging offset: row = tid>>3 (64 rows), source slot (tid&7)^(row&7).
  const int roff = (tid >> 3) * H_DIM + ((((tid & 7) ^ ((tid >> 3) & 7))) << 4);

  // r11's measured-clean read form: rows lane&15 (128-B rows), two b128
  // reads at logical slots {g2, 4+g2}, physical = slot ^ (lane&7).
  const int g2 = lane >> 4;
  const int s0 = ((g2 ^ (lane & 7)) << 4);
  const int s1 = (((4 + g2) ^ (lane & 7)) << 4);
  const int aRowBase = (wm * 64 + (lane & 15)) * 128;
  const int bRowBase = (wn * 64 + (lane & 15)) * 128;

  f32x4 acc[4][4];
#pragma unroll
  for (int i = 0; i < 4; i++)
#pragma unroll
    for (int j = 0; j < 4; j++) { f32x4 z = {0.f, 0.f, 0.f, 0.f}; acc[i][j] = z; }

  // Prologue: B(0)x4 -> bR0, A(0)x2 -> aP0, B(1)x4 -> bR1.
  // vmcnt(4) drains B(0)+A(0), leaves {B(1) x4} = steady-state invariant.
  stage8(Wbase, roff + 0,            lds + 32768 + 0,     tid);
  stage8(Wbase, roff + 64 * H_DIM,   lds + 32768 + 8192,  tid);
  stage8(Wbase, roff + 128 * H_DIM,  lds + 32768 + 16384, tid);
  stage8(Wbase, roff + 192 * H_DIM,  lds + 32768 + 24576, tid);
  stage8(Xbase, roff + 0,            lds + 0,    tid);
  stage8(Xbase, roff + 64 * H_DIM,   lds + 8192, tid);
  stage8(Wbase, roff + 128,               lds + 65536 + 0,     tid);
  stage8(Wbase, roff + 64 * H_DIM + 128,  lds + 65536 + 8192,  tid);
  stage8(Wbase, roff + 128 * H_DIM + 128, lds + 65536 + 16384, tid);
  stage8(Wbase, roff + 192 * H_DIM + 128, lds + 65536 + 24576, tid);
  asm volatile("s_waitcnt vmcnt(4)" ::: "memory");
  BARRIER();

  // Main loop: period lcm(2,3)=6 tiles/iter; tiles 0..29, tail 30,31.
  // In-loop ktB max = 31 (no clamp); tail restages identical data into
  // non-read regions (drained by final vmcnt(0) before LDS reuse).
#pragma unroll 1
  for (int i = 0; i < 5; i++) {
    int g = 6 * i;
    tile_mx<0, 0>(lds, Xbase, Wbase, roff, g + 1, g + 2, tid,
                  aRowBase, bRowBase, s0, s1, acc);
    tile_mx<1, 1>(lds, Xbase, Wbase, roff, g + 2, g + 3, tid,
                  aRowBase, bRowBase, s0, s1, acc);
    tile_mx<0, 2>(lds, Xbase, Wbase, roff, g + 3, g + 4, tid,
                  aRowBase, bRowBase, s0, s1, acc);
    tile_mx<1, 0>(lds, Xbase, Wbase, roff, g + 4, g + 5, tid,
                  aRowBase, bRowBase, s0, s1, acc);
    tile_mx<0, 1>(lds, Xbase, Wbase, roff, g + 5, g + 6, tid,
                  aRowBase, bRowBase, s0, s1, acc);
    tile_mx<1, 2>(lds, Xbase, Wbase, roff, g + 6, g + 7, tid,
                  aRowBase, bRowBase, s0, s1, acc);
  }
  tile_mx<0, 0>(lds, Xbase, Wbase, roff, 31, 31, tid,
                aRowBase, bRowBase, s0, s1, acc);   // tile 30
  tile_mx<1, 1>(lds, Xbase, Wbase, roff, 31, 31, tid,
                aRowBase, bRowBase, s0, s1, acc);   // tile 31

  asm volatile("s_waitcnt vmcnt(0)" ::: "memory");
  __syncthreads();

  // Per-row (max, sum-exp) over this block's 256 vocab columns.
  // 16x16 C/D map (shape-determined): col = lane&15, row = (lane>>4)*4 + q.
  float2* red = (float2*)lds;   // [128 rows][4 wn]
#pragma unroll
  for (int mf = 0; mf < 4; mf++) {
#pragma unroll
    for (int qq = 0; qq < 4; qq++) {
      float v0 = acc[mf][0][qq] * WSCALE_INV, v1 = acc[mf][1][qq] * WSCALE_INV;
      float v2 = acc[mf][2][qq] * WSCALE_INV, v3 = acc[mf][3][qq] * WSCALE_INV;
      float mx = fmaxf(fmaxf(v0, v1), fmaxf(v2, v3));
#pragma unroll
      for (int d = 1; d < 16; d <<= 1) mx = fmaxf(mx, __shfl_xor(mx, d));
      float se = __expf(v0 - mx) + __expf(v1 - mx) + __expf(v2 - mx) + __expf(v3 - mx);
#pragma unroll
      for (int d = 1; d < 16; d <<= 1) se += __shfl_xor(se, d);
      if ((lane & 15) == 0) {
        int row = wm * 64 + mf * 16 + (g2 << 2) + qq;
        float2 v; v.x = mx; v.y = se;
        red[row * 4 + wn] = v;
      }
    }
  }
  __syncthreads();
  if (tid < BM2) {
    float M = -INFINITY, S = 0.f;
#pragma unroll
    for (int w = 0; w < 4; w++) {
      float2 rr = red[tid * 4 + w];
      float Mn = fmaxf(M, rr.x);
      S = S * __expf(M - Mn) + rr.y * __expf(rr.x - Mn);
      M = Mn;
    }
    size_t o = (size_t)ct * N_TOK + mbase + tid;
    pmax[o] = M;
    psum[o] = S;
  }
}

// ---------------- legacy 128^2 kernel, small-ws fallback (fp32 inputs) ------
__global__ __launch_bounds__(256) void gemm_lse_small(
    const float* __restrict__ Xf, const float* __restrict__ Wf,
    float* __restrict__ pmax, float* __restrict__ psum) {
  __shared__ unsigned short As[BM * BK];
  __shared__ unsigned short Bs[BN * BK];
  const int ct = blockIdx.x / MT_NUM;
  const int mt = blockIdx.x % MT_NUM;
  const int mbase = mt * BM, cbase = ct * BN;
  const int tid = threadIdx.x;
  const int lane = tid & 63;
  const int wid = tid >> 6;
  const int wr = wid >> 1, wc = wid & 1;
  f32x4 acc[4][4];
#pragma unroll
  for (int i = 0; i < 4; i++)
#pragma unroll
    for (int j = 0; j < 4; j++) { f32x4 z = {0.f, 0.f, 0.f, 0.f}; acc[i][j] = z; }
  for (int ks = 0; ks < H_DIM / BK; ks++) {
    const int k0 = ks * BK;
#pragma unroll
    for (int r = 0; r < 4; r++) {
      int o = r * 4096 + wid * 1024 + lane * 16;
      int row = o >> 7;
      int kc = (o & 127) >> 1;
      const float* xs = Xf + (size_t)(mbase + row) * H_DIM + k0 + kc;
      const float* wv = Wf + (size_t)(cbase + row) * H_DIM + k0 + kc;
      float4 x0 = *(const float4*)xs, x1 = *(const float4*)(xs + 4);
      float4 w0 = *(const float4*)wv, w1 = *(const float4*)(wv + 4);
      short8 xa, wa;
      xa[0] = f2bf(x0.x); xa[1] = f2bf(x0.y); xa[2] = f2bf(x0.z); xa[3] = f2bf(x0.w);
      xa[4] = f2bf(x1.x); xa[5] = f2bf(x1.y); xa[6] = f2bf(x1.z); xa[7] = f2bf(x1.w);
      wa[0] = f2bf(w0.x); wa[1] = f2bf(w0.y); wa[2] = f2bf(w0.z); wa[3] = f2bf(w0.w);
      wa[4] = f2bf(w1.x); wa[5] = f2bf(w1.y); wa[6] = f2bf(w1.z); wa[7] = f2bf(w1.w);
      *(short8*)((char*)As + o) = xa;
      *(short8*)((char*)Bs + o) = wa;
    }
    __syncthreads();
#pragma unroll
    for (int kk = 0; kk < 2; kk++) {
      short8 a[4], b[4];
#pragma unroll
      for (int m = 0; m < 4; m++)
        a[m] = *(const short8*)((const char*)As +
                (wr * 64 + m * 16 + (lane & 15)) * 128 + kk * 64 + (lane >> 4) * 16);
#pragma unroll
      for (int n = 0; n < 4; n++)
        b[n] = *(const short8*)((const char*)Bs +
                (wc * 64 + n * 16 + (lane & 15)) * 128 + kk * 64 + (lane >> 4) * 16);
#pragma unroll
      for (int m = 0; m < 4; m++)
#pragma unroll
        for (int n = 0; n < 4; n++)
          acc[m][n] = MFMA16(a[m], b[n], acc[m][n]);
    }
    __syncthreads();
  }
  float* red = (float*)As;
  const int g = lane >> 4;
#pragma unroll
  for (int m = 0; m < 4; m++) {
#pragma unroll
    for (int q = 0; q < 4; q++) {
      float v0 = acc[m][0][q], v1 = acc[m][1][q], v2 = acc[m][2][q], v3 = acc[m][3][q];
      float mx = fmaxf(fmaxf(v0, v1), fmaxf(v2, v3));
#pragma unroll
      for (int d = 1; d < 16; d <<= 1) mx = fmaxf(mx, __shfl_xor(mx, d));
      float se = __expf(v0 - mx) + __expf(v1 - mx) + __expf(v2 - mx) + __expf(v3 - mx);
#pragma unroll
      for (int d = 1; d < 16; d <<= 1) se += __shfl_xor(se, d);
      if ((lane & 15) == 0) {
        int row = wr * 64 + m * 16 + g * 4 + q;
        red[row * 4 + wc * 2 + 0] = mx;
        red[row * 4 + wc * 2 + 1] = se;
      }
    }
  }
  __syncthreads();
  if (tid < BM) {
    float m0 = red[tid * 4 + 0], s0 = red[tid * 4 + 1];
    float m1 = red[tid * 4 + 2], s1 = red[tid * 4 + 3];
    float M = fmaxf(m0, m1);
    float S = s0 * __expf(m0 - M) + s1 * __expf(m1 - M);
    size_t o = (size_t)ct * N_TOK + mbase + tid;
    pmax[o] = M;
    psum[o] = S;
  }
}

// ---------------- exact fp32 target logit + reduction kernels ---------------
__global__ __launch_bounds__(256) void target_logit(
    const float* __restrict__ X, const float* __restrict__ W,
    const int* __restrict__ y, float* __restrict__ tl) {
  __shared__ float red[4];
  int row = blockIdx.x;
  int lab = y[row];
  float s = 0.f;
  if (lab >= 0 && lab < V_DIM) {
    const float4* xr = (const float4*)(X + (size_t)row * H_DIM);
    const float4* wr = (const float4*)(W + (size_t)lab * H_DIM);
    for (int i = threadIdx.x; i < H_DIM / 4; i += 256) {
      float4 a = xr[i], b = wr[i];
      s += a.x * b.x + a.y * b.y + a.z * b.z + a.w * b.w;
    }
  }
#pragma unroll
  for (int o = 32; o > 0; o >>= 1) s += __shfl_down(s, o);
  if ((threadIdx.x & 63) == 0) red[threadIdx.x >> 6] = s;
  __syncthreads();
  if (threadIdx.x == 0) tl[row] = red[0] + red[1] + red[2] + red[3];
}

__global__ __launch_bounds__(256) void combine_rows(
    const float* __restrict__ pmax, const float* __restrict__ psum,
    const float* __restrict__ tl, const int* __restrict__ y,
    float* __restrict__ lossb, float* __restrict__ validb, int n_ct) {
  int row = blockIdx.x * 256 + threadIdx.x;
  if (row >= N_TOK) return;
  float M = -INFINITY, S = 0.f;
  for (int ct = 0; ct < n_ct; ct++) {
    float m = pmax[(size_t)ct * N_TOK + row];
    float s = psum[(size_t)ct * N_TOK + row];
    float Mn = fmaxf(M, m);
    S = S * __expf(M - Mn) + s * __expf(m - Mn);
    M = Mn;
  }
  bool valid = (y[row] != -100);
  lossb[row] = valid ? (M + __logf(S) - tl[row]) : 0.f;
  validb[row] = valid ? 1.f : 0.f;
}

__global__ __launch_bounds__(256) void finalize_loss(
    const float* __restrict__ lossb, const float* __restrict__ validb,
    float* __restrict__ out) {
  __shared__ float rs[4], rc[4];
  float s = 0.f, c = 0.f;
  for (int i = threadIdx.x; i < N_TOK; i += 256) { s += lossb[i]; c += validb[i]; }
#pragma unroll
  for (int o = 32; o > 0; o >>= 1) { s += __shfl_down(s, o); c += __shfl_down(c, o); }
  if ((threadIdx.x & 63) == 0) { rs[threadIdx.x >> 6] = s; rc[threadIdx.x >> 6] = c; }
  __syncthreads();
  if (threadIdx.x == 0) {
    float S = rs[0] + rs[1] + rs[2] + rs[3];
    float C = rc[0] + rc[1] + rc[2] + rc[3];
    out[0] = S / fmaxf(C, 1.f);
  }
}

extern "C" void kernel_launch(void* const* d_in, const int* in_sizes, int n_in,
                              void* d_out, int out_size, void* d_ws, size_t ws_size,
                              hipStream_t stream) {
  const float* x = (const float*)d_in[0];
  const int* y = (const int*)d_in[1];
  const float* W = (const float*)d_in[2];
  float* out = (float*)d_out;
  char* ws = (char*)d_ws;

  const size_t szWq = (size_t)V_DIM * H_DIM;        // 131,072,000 (fp8)
  const size_t szXq = (size_t)N_TOK * H_DIM;        //  16,777,216 (fp8)
  const size_t szP  = (size_t)CT_NUM * N_TOK * 4;   // sized for 250-tile fallback
  const size_t szT  = (size_t)N_TOK * 4;
  const size_t needFull = szWq + szXq + 2 * szP + 3 * szT;

  bool full = (ws_size >= needFull);
  uint8_t* Wq = nullptr;
  uint8_t* Xq = nullptr;
  size_t off = 0;
  if (full) { Wq = (uint8_t*)ws; Xq = (uint8_t*)(ws + szWq); off = szWq + szXq; }
  float* pmax   = (float*)(ws + off); off += szP;
  float* psum   = (float*)(ws + off); off += szP;
  float* tl     = (float*)(ws + off); off += szT;
  float* lossb  = (float*)(ws + off); off += szT;
  float* validb = (float*)(ws + off);

  if (full) {
    cast_f32_to_fp8_k128<<<8192, 256, 0, stream>>>(
        W, (uint4*)Wq, (long)(szWq / 16), WSCALE);
    cast_f32_to_fp8_k128<<<2048, 256, 0, stream>>>(
        x, (uint4*)Xq, (long)(szXq / 16), 1.0f);
    (void)hipFuncSetAttribute((const void*)gemm_lse8,
        hipFuncAttributeMaxDynamicSharedMemorySize, 131072);
    gemm_lse8<<<CT2 * MT2, 512, 131072, stream>>>(Xq, Wq, pmax, psum);
    target_logit<<<N_TOK, 256, 0, stream>>>(x, W, y, tl);
    combine_rows<<<N_TOK / 256, 256, 0, stream>>>(pmax, psum, tl, y, lossb, validb, CT2);
  } else {
    gemm_lse_small<<<CT_NUM * MT_NUM, 256, 0, stream>>>(x, W, pmax, psum);
    target_logit<<<N_TOK, 256, 0, stream>>>(x, W, y, tl);
    combine_rows<<<N_TOK / 256, 256, 0, stream>>>(pmax, psum, tl, y, lossb, validb, CT_NUM);
  }
  finalize_loss<<<1, 256, 0, stream>>>(lossb, validb, out);
}

// Round 20
// 756.932 us; speedup vs baseline: 1.4474x; 1.0183x over previous
//
#include <hip/hip_runtime.h>
#include <stdint.h>
#include <math.h>

#define N_TOK 4096
#define H_DIM 4096
#define V_DIM 32000

// ---- 2-phase 128x256 MX-fp8 GEMM geometry (BK=128, kk-packed slots) ----
#define BM2 128
#define BN2 256
#define BK2 128
#define NKT2 (H_DIM / BK2)    // 32 K-tiles
#define CT2 (V_DIM / BN2)     // 125 column tiles
#define MT2 (N_TOK / BM2)     // 32 row tiles -> 4000 blocks (4000%8==0)
#define WSCALE 16.0f          // W pre-scale (avoids e4m3 subnormals)
#define WSCALE_INV 0.0625f

// ---- legacy 128x128 fallback geometry (small-ws, fp32 inputs) ----
#define BM 128
#define BN 128
#define BK 64
#define CT_NUM (V_DIM / BN)   // 250
#define MT_NUM (N_TOK / BM)   // 32

typedef __attribute__((ext_vector_type(8))) short short8;
typedef __attribute__((ext_vector_type(4))) float f32x4;
typedef __attribute__((ext_vector_type(4))) int i32x4;
typedef __attribute__((ext_vector_type(8))) int i32x8;

#define MFMA16(a, b, c) __builtin_amdgcn_mfma_f32_16x16x32_bf16(a, b, c, 0, 0, 0)
// cbsz/blgp = 0 (e4m3 A and B); scale words 0x7f7f7f7f = E8M0 exp 0 (x1.0).
#define MFMAMX(a, b, c) __builtin_amdgcn_mfma_scale_f32_16x16x128_f8f6f4( \
    a, b, c, 0, 0, 0, 0x7f7f7f7f, 0, 0x7f7f7f7f)
#define BARRIER() asm volatile("s_barrier" ::: "memory")

__device__ __forceinline__ unsigned short f2bf(float x) {
  union { float f; unsigned int u; } v; v.f = x;
  unsigned int r = v.u + 0x7fffu + ((v.u >> 16) & 1u);
  return (unsigned short)(r >> 16);
}

__device__ __forceinline__ unsigned int pk4(float a, float b, float c, float d) {
  int v = __builtin_amdgcn_cvt_pk_fp8_f32(a, b, 0, false);
  v = __builtin_amdgcn_cvt_pk_fp8_f32(c, d, v, true);
  return (unsigned int)v;
}

__device__ __forceinline__ void async16(const void* g, void* lds) {
  __builtin_amdgcn_global_load_lds(
      (const __attribute__((address_space(1))) void*)g,
      (__attribute__((address_space(3))) void*)lds, 16, 0, 0);
}

// f32 -> fp8 e4m3 with per-128-block kk-packing: slot s (16B) of block b,
// with t=s>>2, g=s&3, holds bytes [h=0: k=64t+8g+e][h=1: k=64t+32+8g+e].
// Feeding MFMAMX the i32x8 from slots {g2, 4+g2} applies the SAME
// k-permutation to A and B -> exact dot product (scales are 1.0).
__global__ __launch_bounds__(256) void cast_f32_to_fp8_k128(
    const float* __restrict__ in, uint4* __restrict__ out, long nslots,
    float scale) {
  long stride = (long)gridDim.x * blockDim.x;
  for (long slot = (long)blockIdx.x * blockDim.x + threadIdx.x; slot < nslots;
       slot += stride) {
    long b = slot >> 3;
    int s = (int)(slot & 7);
    int t = s >> 2, g = s & 3;
    const float* p0 = in + b * 128 + t * 64 + g * 8;   // h = 0
    const float* p1 = p0 + 32;                          // h = 1
    float4 a0 = *(const float4*)p0, a1 = *(const float4*)(p0 + 4);
    float4 c0 = *(const float4*)p1, c1 = *(const float4*)(p1 + 4);
    uint4 o;
    o.x = pk4(a0.x * scale, a0.y * scale, a0.z * scale, a0.w * scale);
    o.y = pk4(a1.x * scale, a1.y * scale, a1.z * scale, a1.w * scale);
    o.z = pk4(c0.x * scale, c0.y * scale, c0.z * scale, c0.w * scale);
    o.w = pk4(c1.x * scale, c1.y * scale, c1.z * scale, c1.w * scale);
    out[slot] = o;
  }
}

// Stage one 64-row x 128-B chunk (8 KB), 512 threads, 1 DMA instr/wave.
// LDS dest linear; XOR swizzle (phys slot p holds logical slot p^(r&7))
// carried by the SOURCE address via roff.
__device__ __forceinline__ void stage8(const uint8_t* __restrict__ base,
                                       int off, char* dest, int tid) {
  async16(base + off, dest + (tid >> 6) * 1024);
}

// One 32-B f8f6f4 operand from two swizzled ds_read_b128 (r11 clean form).
__device__ __forceinline__ i32x8 ld_op(const char* base, int rowByte,
                                       int s0, int s1) {
  i32x4 lo = *(const i32x4*)(base + rowByte + s0);
  i32x4 hi = *(const i32x4*)(base + rowByte + s1);
  i32x8 r;
  r[0] = lo[0]; r[1] = lo[1]; r[2] = lo[2]; r[3] = lo[3];
  r[4] = hi[0]; r[5] = hi[1]; r[6] = hi[2]; r[7] = hi[3];
  return r;
}

// One BK=128 K-tile g, TWO phases, ONE {vmcnt(4); barrier} per tile.
// NEW vs r15/r19: the 4 A-fragments are loaded ONCE per tile (32 VGPRs,
// live across both phases) instead of re-read in phase1 -- LDS reads drop
// from 24 to 16 b128/wave/tile, attacking the measured binding pipe
// (LDS 2304 cyc vs MFMA 1106 cyc vs wall 2769 per CU per tile).
// A dbuf 2x16KB: read AP=g&1, stage A(g+1) -> AP^1 in phase0. B tribuf
// 3x32KB: read BR=g%3, stage B(g+2) -> (BR+2)%3 in phase1 -- staging
// never touches a read region. vmcnt FIFO (2A+4B=6 DMA/tile): entering
// phase0 outstanding = {B(g+1) x4}; +2A -> 6; +4B -> 10; vmcnt(4) drains
// B(g+1)x4 + A(g+1)x2 (needed next tile, ~1-phase slack), leaves
// {B(g+2) x4} -> invariant.
template<int AP, int BR>
__device__ __forceinline__ void tile_mx(char* lds,
    const uint8_t* __restrict__ Xbase, const uint8_t* __restrict__ Wbase,
    int roff, int ktA, int ktB, int tid,
    int aRowBase, int bRowBase, int s0, int s1, f32x4 (&acc)[4][4]) {
  const char* aB = lds + AP * 16384;
  char* aN = lds + (AP ^ 1) * 16384;
  const char* bB = lds + 32768 + BR * 32768;
  char* bN = lds + 32768 + ((BR + 2) % 3) * 32768;
  const int kA = ktA * 128, kB = ktB * 128;

  // ---- phase 0: load A once; n-frags 0,1; stage A(g+1) ----
  stage8(Xbase, roff + kA,              aN + 0,    tid);
  stage8(Xbase, roff + 64 * H_DIM + kA, aN + 8192, tid);
  i32x8 a0 = ld_op(aB, aRowBase + 0,    s0, s1);
  i32x8 a1 = ld_op(aB, aRowBase + 2048, s0, s1);
  i32x8 a2 = ld_op(aB, aRowBase + 4096, s0, s1);
  i32x8 a3 = ld_op(aB, aRowBase + 6144, s0, s1);
  {
    i32x8 b0 = ld_op(bB, bRowBase + 0,    s0, s1);
    i32x8 b1 = ld_op(bB, bRowBase + 2048, s0, s1);
    __builtin_amdgcn_s_setprio(1);
    acc[0][0] = MFMAMX(a0, b0, acc[0][0]);
    acc[1][0] = MFMAMX(a1, b0, acc[1][0]);
    acc[2][0] = MFMAMX(a2, b0, acc[2][0]);
    acc[3][0] = MFMAMX(a3, b0, acc[3][0]);
    acc[0][1] = MFMAMX(a0, b1, acc[0][1]);
    acc[1][1] = MFMAMX(a1, b1, acc[1][1]);
    acc[2][1] = MFMAMX(a2, b1, acc[2][1]);
    acc[3][1] = MFMAMX(a3, b1, acc[3][1]);
    __builtin_amdgcn_s_setprio(0);
  }
  __builtin_amdgcn_sched_barrier(0);

  // ---- phase 1: n-frags 2,3 (A reused from registers); stage B(g+2) ----
  stage8(Wbase, roff + kB,               bN + 0,     tid);
  stage8(Wbase, roff + 64 * H_DIM + kB,  bN + 8192,  tid);
  stage8(Wbase, roff + 128 * H_DIM + kB, bN + 16384, tid);
  stage8(Wbase, roff + 192 * H_DIM + kB, bN + 24576, tid);
  {
    i32x8 b2 = ld_op(bB, bRowBase + 4096, s0, s1);
    i32x8 b3 = ld_op(bB, bRowBase + 6144, s0, s1);
    __builtin_amdgcn_s_setprio(1);
    acc[0][2] = MFMAMX(a0, b2, acc[0][2]);
    acc[1][2] = MFMAMX(a1, b2, acc[1][2]);
    acc[2][2] = MFMAMX(a2, b2, acc[2][2]);
    acc[3][2] = MFMAMX(a3, b2, acc[3][2]);
    acc[0][3] = MFMAMX(a0, b3, acc[0][3]);
    acc[1][3] = MFMAMX(a1, b3, acc[1][3]);
    acc[2][3] = MFMAMX(a2, b3, acc[2][3]);
    acc[3][3] = MFMAMX(a3, b3, acc[3][3]);
    __builtin_amdgcn_s_setprio(0);
  }
  __builtin_amdgcn_sched_barrier(0);
  asm volatile("s_waitcnt vmcnt(4)" ::: "memory");
  BARRIER();
}

__global__ __launch_bounds__(512, 2) void gemm_lse8(
    const uint8_t* __restrict__ Xq, const uint8_t* __restrict__ Wq,
    float* __restrict__ pmax, float* __restrict__ psum) {
  extern __shared__ char lds[];
  const int tid = threadIdx.x;
  const int lane = tid & 63;
  const int wid = tid >> 6;
  const int wm = wid >> 2, wn = wid & 3;   // 2m x 4n waves; 64x64 out each

  // XCD-aware swizzle (4000 % 8 == 0 -> bijective), mt-fastest for W reuse.
  int logical = (blockIdx.x & 7) * (CT2 * MT2 / 8) + (blockIdx.x >> 3);
  const int ct = logical / MT2, mt = logical - ct * MT2;
  const int mbase = mt * BM2, cbase = ct * BN2;
  const uint8_t* Xbase = Xq + (size_t)mbase * H_DIM;
  const uint8_t* Wbase = Wq + (size_t)cbase * H_DIM;

  // Staging offset: row = tid>>3 (64 rows), source slot (tid&7)^(row&7).
  const int roff = (tid >> 3) * H_DIM + ((((tid & 7) ^ ((tid >> 3) & 7))) << 4);

  // r11's measured-clean read form: rows lane&15 (128-B rows), two b128
  // reads at logical slots {g2, 4+g2}, physical = slot ^ (lane&7).
  const int g2 = lane >> 4;
  const int s0 = ((g2 ^ (lane & 7)) << 4);
  const int s1 = (((4 + g2) ^ (lane & 7)) << 4);
  const int aRowBase = (wm * 64 + (lane & 15)) * 128;
  const int bRowBase = (wn * 64 + (lane & 15)) * 128;

  f32x4 acc[4][4];
#pragma unroll
  for (int i = 0; i < 4; i++)
#pragma unroll
    for (int j = 0; j < 4; j++) { f32x4 z = {0.f, 0.f, 0.f, 0.f}; acc[i][j] = z; }

  // Prologue: B(0)x4 -> bR0, A(0)x2 -> aP0, B(1)x4 -> bR1.
  // vmcnt(4) drains B(0)+A(0), leaves {B(1) x4} = steady-state invariant.
  stage8(Wbase, roff + 0,            lds + 32768 + 0,     tid);
  stage8(Wbase, roff + 64 * H_DIM,   lds + 32768 + 8192,  tid);
  stage8(Wbase, roff + 128 * H_DIM,  lds + 32768 + 16384, tid);
  stage8(Wbase, roff + 192 * H_DIM,  lds + 32768 + 24576, tid);
  stage8(Xbase, roff + 0,            lds + 0,    tid);
  stage8(Xbase, roff + 64 * H_DIM,   lds + 8192, tid);
  stage8(Wbase, roff + 128,               lds + 65536 + 0,     tid);
  stage8(Wbase, roff + 64 * H_DIM + 128,  lds + 65536 + 8192,  tid);
  stage8(Wbase, roff + 128 * H_DIM + 128, lds + 65536 + 16384, tid);
  stage8(Wbase, roff + 192 * H_DIM + 128, lds + 65536 + 24576, tid);
  asm volatile("s_waitcnt vmcnt(4)" ::: "memory");
  BARRIER();

  // Main loop: period lcm(2,3)=6 tiles/iter; tiles 0..29, tail 30,31.
  // In-loop ktB max = 31 (no clamp); tail restages identical data into
  // non-read regions (drained by final vmcnt(0) before LDS reuse).
#pragma unroll 1
  for (int i = 0; i < 5; i++) {
    int g = 6 * i;
    tile_mx<0, 0>(lds, Xbase, Wbase, roff, g + 1, g + 2, tid,
                  aRowBase, bRowBase, s0, s1, acc);
    tile_mx<1, 1>(lds, Xbase, Wbase, roff, g + 2, g + 3, tid,
                  aRowBase, bRowBase, s0, s1, acc);
    tile_mx<0, 2>(lds, Xbase, Wbase, roff, g + 3, g + 4, tid,
                  aRowBase, bRowBase, s0, s1, acc);
    tile_mx<1, 0>(lds, Xbase, Wbase, roff, g + 4, g + 5, tid,
                  aRowBase, bRowBase, s0, s1, acc);
    tile_mx<0, 1>(lds, Xbase, Wbase, roff, g + 5, g + 6, tid,
                  aRowBase, bRowBase, s0, s1, acc);
    tile_mx<1, 2>(lds, Xbase, Wbase, roff, g + 6, g + 7, tid,
                  aRowBase, bRowBase, s0, s1, acc);
  }
  tile_mx<0, 0>(lds, Xbase, Wbase, roff, 31, 31, tid,
                aRowBase, bRowBase, s0, s1, acc);   // tile 30
  tile_mx<1, 1>(lds, Xbase, Wbase, roff, 31, 31, tid,
                aRowBase, bRowBase, s0, s1, acc);   // tile 31

  asm volatile("s_waitcnt vmcnt(0)" ::: "memory");
  __syncthreads();

  // Per-row (max, sum-exp) over this block's 256 vocab columns.
  // 16x16 C/D map (shape-determined): col = lane&15, row = (lane>>4)*4 + q.
  float2* red = (float2*)lds;   // [128 rows][4 wn]
#pragma unroll
  for (int mf = 0; mf < 4; mf++) {
#pragma unroll
    for (int qq = 0; qq < 4; qq++) {
      float v0 = acc[mf][0][qq] * WSCALE_INV, v1 = acc[mf][1][qq] * WSCALE_INV;
      float v2 = acc[mf][2][qq] * WSCALE_INV, v3 = acc[mf][3][qq] * WSCALE_INV;
      float mx = fmaxf(fmaxf(v0, v1), fmaxf(v2, v3));
#pragma unroll
      for (int d = 1; d < 16; d <<= 1) mx = fmaxf(mx, __shfl_xor(mx, d));
      float se = __expf(v0 - mx) + __expf(v1 - mx) + __expf(v2 - mx) + __expf(v3 - mx);
#pragma unroll
      for (int d = 1; d < 16; d <<= 1) se += __shfl_xor(se, d);
      if ((lane & 15) == 0) {
        int row = wm * 64 + mf * 16 + (g2 << 2) + qq;
        float2 v; v.x = mx; v.y = se;
        red[row * 4 + wn] = v;
      }
    }
  }
  __syncthreads();
  if (tid < BM2) {
    float M = -INFINITY, S = 0.f;
#pragma unroll
    for (int w = 0; w < 4; w++) {
      float2 rr = red[tid * 4 + w];
      float Mn = fmaxf(M, rr.x);
      S = S * __expf(M - Mn) + rr.y * __expf(rr.x - Mn);
      M = Mn;
    }
    size_t o = (size_t)ct * N_TOK + mbase + tid;
    pmax[o] = M;
    psum[o] = S;
  }
}

// ---------------- legacy 128^2 kernel, small-ws fallback (fp32 inputs) ------
__global__ __launch_bounds__(256) void gemm_lse_small(
    const float* __restrict__ Xf, const float* __restrict__ Wf,
    float* __restrict__ pmax, float* __restrict__ psum) {
  __shared__ unsigned short As[BM * BK];
  __shared__ unsigned short Bs[BN * BK];
  const int ct = blockIdx.x / MT_NUM;
  const int mt = blockIdx.x % MT_NUM;
  const int mbase = mt * BM, cbase = ct * BN;
  const int tid = threadIdx.x;
  const int lane = tid & 63;
  const int wid = tid >> 6;
  const int wr = wid >> 1, wc = wid & 1;
  f32x4 acc[4][4];
#pragma unroll
  for (int i = 0; i < 4; i++)
#pragma unroll
    for (int j = 0; j < 4; j++) { f32x4 z = {0.f, 0.f, 0.f, 0.f}; acc[i][j] = z; }
  for (int ks = 0; ks < H_DIM / BK; ks++) {
    const int k0 = ks * BK;
#pragma unroll
    for (int r = 0; r < 4; r++) {
      int o = r * 4096 + wid * 1024 + lane * 16;
      int row = o >> 7;
      int kc = (o & 127) >> 1;
      const float* xs = Xf + (size_t)(mbase + row) * H_DIM + k0 + kc;
      const float* wv = Wf + (size_t)(cbase + row) * H_DIM + k0 + kc;
      float4 x0 = *(const float4*)xs, x1 = *(const float4*)(xs + 4);
      float4 w0 = *(const float4*)wv, w1 = *(const float4*)(wv + 4);
      short8 xa, wa;
      xa[0] = f2bf(x0.x); xa[1] = f2bf(x0.y); xa[2] = f2bf(x0.z); xa[3] = f2bf(x0.w);
      xa[4] = f2bf(x1.x); xa[5] = f2bf(x1.y); xa[6] = f2bf(x1.z); xa[7] = f2bf(x1.w);
      wa[0] = f2bf(w0.x); wa[1] = f2bf(w0.y); wa[2] = f2bf(w0.z); wa[3] = f2bf(w0.w);
      wa[4] = f2bf(w1.x); wa[5] = f2bf(w1.y); wa[6] = f2bf(w1.z); wa[7] = f2bf(w1.w);
      *(short8*)((char*)As + o) = xa;
      *(short8*)((char*)Bs + o) = wa;
    }
    __syncthreads();
#pragma unroll
    for (int kk = 0; kk < 2; kk++) {
      short8 a[4], b[4];
#pragma unroll
      for (int m = 0; m < 4; m++)
        a[m] = *(const short8*)((const char*)As +
                (wr * 64 + m * 16 + (lane & 15)) * 128 + kk * 64 + (lane >> 4) * 16);
#pragma unroll
      for (int n = 0; n < 4; n++)
        b[n] = *(const short8*)((const char*)Bs +
                (wc * 64 + n * 16 + (lane & 15)) * 128 + kk * 64 + (lane >> 4) * 16);
#pragma unroll
      for (int m = 0; m < 4; m++)
#pragma unroll
        for (int n = 0; n < 4; n++)
          acc[m][n] = MFMA16(a[m], b[n], acc[m][n]);
    }
    __syncthreads();
  }
  float* red = (float*)As;
  const int g = lane >> 4;
#pragma unroll
  for (int m = 0; m < 4; m++) {
#pragma unroll
    for (int q = 0; q < 4; q++) {
      float v0 = acc[m][0][q], v1 = acc[m][1][q], v2 = acc[m][2][q], v3 = acc[m][3][q];
      float mx = fmaxf(fmaxf(v0, v1), fmaxf(v2, v3));
#pragma unroll
      for (int d = 1; d < 16; d <<= 1) mx = fmaxf(mx, __shfl_xor(mx, d));
      float se = __expf(v0 - mx) + __expf(v1 - mx) + __expf(v2 - mx) + __expf(v3 - mx);
#pragma unroll
      for (int d = 1; d < 16; d <<= 1) se += __shfl_xor(se, d);
      if ((lane & 15) == 0) {
        int row = wr * 64 + m * 16 + g * 4 + q;
        red[row * 4 + wc * 2 + 0] = mx;
        red[row * 4 + wc * 2 + 1] = se;
      }
    }
  }
  __syncthreads();
  if (tid < BM) {
    float m0 = red[tid * 4 + 0], s0 = red[tid * 4 + 1];
    float m1 = red[tid * 4 + 2], s1 = red[tid * 4 + 3];
    float M = fmaxf(m0, m1);
    float S = s0 * __expf(m0 - M) + s1 * __expf(m1 - M);
    size_t o = (size_t)ct * N_TOK + mbase + tid;
    pmax[o] = M;
    psum[o] = S;
  }
}

// ---------------- exact fp32 target logit + reduction kernels ---------------
__global__ __launch_bounds__(256) void target_logit(
    const float* __restrict__ X, const float* __restrict__ W,
    const int* __restrict__ y, float* __restrict__ tl) {
  __shared__ float red[4];
  int row = blockIdx.x;
  int lab = y[row];
  float s = 0.f;
  if (lab >= 0 && lab < V_DIM) {
    const float4* xr = (const float4*)(X + (size_t)row * H_DIM);
    const float4* wr = (const float4*)(W + (size_t)lab * H_DIM);
    for (int i = threadIdx.x; i < H_DIM / 4; i += 256) {
      float4 a = xr[i], b = wr[i];
      s += a.x * b.x + a.y * b.y + a.z * b.z + a.w * b.w;
    }
  }
#pragma unroll
  for (int o = 32; o > 0; o >>= 1) s += __shfl_down(s, o);
  if ((threadIdx.x & 63) == 0) red[threadIdx.x >> 6] = s;
  __syncthreads();
  if (threadIdx.x == 0) tl[row] = red[0] + red[1] + red[2] + red[3];
}

__global__ __launch_bounds__(256) void combine_rows(
    const float* __restrict__ pmax, const float* __restrict__ psum,
    const float* __restrict__ tl, const int* __restrict__ y,
    float* __restrict__ lossb, float* __restrict__ validb, int n_ct) {
  int row = blockIdx.x * 256 + threadIdx.x;
  if (row >= N_TOK) return;
  float M = -INFINITY, S = 0.f;
  for (int ct = 0; ct < n_ct; ct++) {
    float m = pmax[(size_t)ct * N_TOK + row];
    float s = psum[(size_t)ct * N_TOK + row];
    float Mn = fmaxf(M, m);
    S = S * __expf(M - Mn) + s * __expf(m - Mn);
    M = Mn;
  }
  bool valid = (y[row] != -100);
  lossb[row] = valid ? (M + __logf(S) - tl[row]) : 0.f;
  validb[row] = valid ? 1.f : 0.f;
}

__global__ __launch_bounds__(256) void finalize_loss(
    const float* __restrict__ lossb, const float* __restrict__ validb,
    float* __restrict__ out) {
  __shared__ float rs[4], rc[4];
  float s = 0.f, c = 0.f;
  for (int i = threadIdx.x; i < N_TOK; i += 256) { s += lossb[i]; c += validb[i]; }
#pragma unroll
  for (int o = 32; o > 0; o >>= 1) { s += __shfl_down(s, o); c += __shfl_down(c, o); }
  if ((threadIdx.x & 63) == 0) { rs[threadIdx.x >> 6] = s; rc[threadIdx.x >> 6] = c; }
  __syncthreads();
  if (threadIdx.x == 0) {
    float S = rs[0] + rs[1] + rs[2] + rs[3];
    float C = rc[0] + rc[1] + rc[2] + rc[3];
    out[0] = S / fmaxf(C, 1.f);
  }
}

extern "C" void kernel_launch(void* const* d_in, const int* in_sizes, int n_in,
                              void* d_out, int out_size, void* d_ws, size_t ws_size,
                              hipStream_t stream) {
  const float* x = (const float*)d_in[0];
  const int* y = (const int*)d_in[1];
  const float* W = (const float*)d_in[2];
  float* out = (float*)d_out;
  char* ws = (char*)d_ws;

  const size_t szWq = (size_t)V_DIM * H_DIM;        // 131,072,000 (fp8)
  const size_t szXq = (size_t)N_TOK * H_DIM;        //  16,777,216 (fp8)
  const size_t szP  = (size_t)CT_NUM * N_TOK * 4;   // sized for 250-tile fallback
  const size_t szT  = (size_t)N_TOK * 4;
  const size_t needFull = szWq + szXq + 2 * szP + 3 * szT;

  bool full = (ws_size >= needFull);
  uint8_t* Wq = nullptr;
  uint8_t* Xq = nullptr;
  size_t off = 0;
  if (full) { Wq = (uint8_t*)ws; Xq = (uint8_t*)(ws + szWq); off = szWq + szXq; }
  float* pmax   = (float*)(ws + off); off += szP;
  float* psum   = (float*)(ws + off); off += szP;
  float* tl     = (float*)(ws + off); off += szT;
  float* lossb  = (float*)(ws + off); off += szT;
  float* validb = (float*)(ws + off);

  if (full) {
    cast_f32_to_fp8_k128<<<8192, 256, 0, stream>>>(
        W, (uint4*)Wq, (long)(szWq / 16), WSCALE);
    cast_f32_to_fp8_k128<<<2048, 256, 0, stream>>>(
        x, (uint4*)Xq, (long)(szXq / 16), 1.0f);
    (void)hipFuncSetAttribute((const void*)gemm_lse8,
        hipFuncAttributeMaxDynamicSharedMemorySize, 131072);
    gemm_lse8<<<CT2 * MT2, 512, 131072, stream>>>(Xq, Wq, pmax, psum);
    target_logit<<<N_TOK, 256, 0, stream>>>(x, W, y, tl);
    combine_rows<<<N_TOK / 256, 256, 0, stream>>>(pmax, psum, tl, y, lossb, validb, CT2);
  } else {
    gemm_lse_small<<<CT_NUM * MT_NUM, 256, 0, stream>>>(x, W, pmax, psum);
    target_logit<<<N_TOK, 256, 0, stream>>>(x, W, y, tl);
    combine_rows<<<N_TOK / 256, 256, 0, stream>>>(pmax, psum, tl, y, lossb, validb, CT_NUM);
  }
  finalize_loss<<<1, 256, 0, stream>>>(lossb, validb, out);
}